// Round 10
// baseline (328.000 us; speedup 1.0000x reference)
//
#include <hip/hip_runtime.h>
#include <math.h>

// Problem constants (GATModel: N=50000, E=800000, F_IN=128, HID=OUT=64, H=4)
constexpr int NNODE = 50000;
constexpr int FIN   = 128;
constexpr int HID   = 64;
constexpr int NH    = 4;
constexpr int NC    = 256;   // NH * HID
constexpr float NEG = 0.2f;
constexpr int MPAD  = 50048; // NNODE padded to 64-row tiles (782*64)
constexpr int SCANB = (NNODE + 255) / 256;  // 196
constexpr int NCPY  = 4;     // histogram copies (atomic contention 16-way -> 4-way)

typedef unsigned short u16;
typedef unsigned int   u32;
typedef __fp16 h16x8 __attribute__((ext_vector_type(8)));
typedef __fp16 h2    __attribute__((ext_vector_type(2)));
typedef float  f32x4 __attribute__((ext_vector_type(4)));

__device__ __forceinline__ u16 f2h(float f) {
  union { __fp16 h; u16 u; } c; c.h = (__fp16)f; return c.u;
}
__device__ __forceinline__ h2 u2h2(u32 u) {
  union { u32 u; h2 h; } c; c.u = u; return c.h;
}
__device__ __forceinline__ float readlane_f(float v, int l) {
  return __int_as_float(__builtin_amdgcn_readlane(__float_as_int(v), l));
}
// fp16 bits -> bf8(e5m2) bits, round-to-nearest-even (e5m2 = truncated fp16)
__device__ __forceinline__ u32 h2bf8(u16 hx) {
  return ((u32)hx + 0x7Fu + ((hx >> 8) & 1u)) >> 8;
}

// ---------------- kernel 1: weight packing + deg4 zeroing ----------------
__global__ __launch_bounds__(256) void pack_zero(const float* __restrict__ W1,
                                                 const float* __restrict__ W2,
                                                 u16* __restrict__ Bp1, u16* __restrict__ Bp2,
                                                 int* __restrict__ deg4, int packBlocks, int n) {
  int b = blockIdx.x;
  if (b < packBlocks) {
    int i = b * 256 + threadIdx.x;
    const int t1 = FIN * NC;
    const int t2 = HID * NC;
    if (i < t1) {
      int k = i >> 8, c = i & 255;
      Bp1[((size_t)(k >> 3) * 256 + c) * 8 + (k & 7)] = f2h(W1[i]);
    } else if (i < t1 + t2) {
      int j = i - t1;
      int k = j >> 8, c = j & 255;
      Bp2[((size_t)(k >> 3) * 256 + c) * 8 + (k & 7)] = f2h(W2[j]);
    }
  } else {
    int i = (b - packBlocks) * 256 + threadIdx.x;
    if (i < NCPY * n) deg4[i] = 0;
  }
}

// ---------------- MFMA fp16 GEMM body ----------------
// C[M,256] = A[M,K] @ B[K,256]fp16 (B pre-packed in fragment order).
// A-frag: lane holds A[m = lane&15][k = (lane>>4)*8 + j]
// B-frag: lane holds B[k = (lane>>4)*8 + j][n = lane&15]  (packed Bp)
// D: col = lane&15, row = (lane>>4)*4 + reg   [m89/m91-verified layouts]
// F8: feature store as bf8(e5m2) packed 4 heads/u32 at [node][channel][head] (256B rows);
//     else fp16 at [node][c][h] (512B rows).
template <int KS, bool AF32, bool F8>  // K = 32*KS
__device__ __forceinline__ void gemm_body(
    int bx, const void* __restrict__ Aptr, const u16* __restrict__ Bp,
    const float* __restrict__ a_s, const float* __restrict__ a_d,
    void* __restrict__ feat, float* __restrict__ al_s, float* __restrict__ al_d, int M) {
  const int K = 32 * KS;
  int lane = threadIdx.x & 63;
  int wv = threadIdx.x >> 6;
  int q = lane >> 4, r = lane & 15;
  int m0 = bx * 64 + wv * 16;

  h16x8 af[KS];
  if (AF32) {
    int ar = m0 + r; if (ar >= M) ar = M - 1;   // x has exactly M rows; clamp (stores guarded)
    const float* arow = (const float*)Aptr + (size_t)ar * K + q * 8;
#pragma unroll
    for (int ks = 0; ks < KS; ++ks) {
      float4 v0 = *(const float4*)(arow + ks * 32);
      float4 v1 = *(const float4*)(arow + ks * 32 + 4);
      union { h16x8 v; h2 p[4]; } u;
      u.p[0] = __builtin_amdgcn_cvt_pkrtz(v0.x, v0.y);
      u.p[1] = __builtin_amdgcn_cvt_pkrtz(v0.z, v0.w);
      u.p[2] = __builtin_amdgcn_cvt_pkrtz(v1.x, v1.y);
      u.p[3] = __builtin_amdgcn_cvt_pkrtz(v1.z, v1.w);
      af[ks] = u.v;
    }
  } else {
    const u16* arow = (const u16*)Aptr + (size_t)(m0 + r) * K + q * 8;  // padded buffer
#pragma unroll
    for (int ks = 0; ks < KS; ++ks) af[ks] = *(const h16x8*)(arow + ks * 32);
  }

  int node_base = m0 + q * 4;
  u32 pk8[4][4];
  if (F8) {
#pragma unroll
    for (int a = 0; a < 4; ++a)
#pragma unroll
      for (int b = 0; b < 4; ++b) pk8[a][b] = 0u;
  }
#pragma unroll
  for (int h = 0; h < NH; ++h) {
    f32x4 acc[4];
#pragma unroll
    for (int c4 = 0; c4 < 4; ++c4) {
      acc[c4] = (f32x4){0.f, 0.f, 0.f, 0.f};
      const u16* bp = Bp + ((size_t)q * 256 + (h * 4 + c4) * 16 + r) * 8;
#pragma unroll
      for (int ks = 0; ks < KS; ++ks) {
        h16x8 bf = *(const h16x8*)(bp + (size_t)ks * 4 * 256 * 8);
        acc[c4] = __builtin_amdgcn_mfma_f32_16x16x32_f16(af[ks], bf, acc[c4], 0, 0, 0);
      }
    }
    // epilogue for this head: alpha partials + packed stores
    float ps[4] = {0.f, 0.f, 0.f, 0.f}, pd[4] = {0.f, 0.f, 0.f, 0.f};
#pragma unroll
    for (int c4 = 0; c4 < 4; ++c4) {
      float sa = a_s[h * HID + c4 * 16 + r];
      float da = a_d[h * HID + c4 * 16 + r];
#pragma unroll
      for (int reg = 0; reg < 4; ++reg) {
        float v = acc[c4][reg];
        ps[reg] += v * sa;
        pd[reg] += v * da;
        if (F8) {
          pk8[c4][reg] |= h2bf8(f2h(v)) << (8 * h);
        } else {
          int node = node_base + reg;
          if (node < M) ((u16*)feat)[(size_t)node * NC + (c4 * 16 + r) * NH + h] = f2h(v);
        }
      }
    }
#pragma unroll
    for (int reg = 0; reg < 4; ++reg) {
#pragma unroll
      for (int o = 1; o < 16; o <<= 1) {
        ps[reg] += __shfl_xor(ps[reg], o);
        pd[reg] += __shfl_xor(pd[reg], o);
      }
      int node = node_base + reg;
      if (r == 0 && node < M) {
        al_s[node * NH + h] = ps[reg];
        al_d[node * NH + h] = pd[reg];
      }
    }
  }
  if (F8) {
    // one u32 store per (c4,reg): 4 bf8 heads of channel c4*16+r for node node_base+reg
#pragma unroll
    for (int c4 = 0; c4 < 4; ++c4)
#pragma unroll
      for (int reg = 0; reg < 4; ++reg) {
        int node = node_base + reg;
        if (node < M)
          *(u32*)((char*)feat + (size_t)node * 256 + (c4 * 16 + r) * 4) = pk8[c4][reg];
      }
  }
}

// ---------------- kernel 2: degree count (4-copy atomics) ∥ gemm layer-1 (MFMA) ----
// Gemm blocks FIRST; the 3125 atomic-bound count blocks fill memory pipes around them.
// Copy c = edge-block&3 quarters same-address atomic serialization (16-way avg -> 4).
__global__ __launch_bounds__(256) void count_gemm1(
    const float* __restrict__ x, const u16* __restrict__ Bp1,
    const float* __restrict__ a_s, const float* __restrict__ a_d,
    void* __restrict__ hf8, float* __restrict__ al_s, float* __restrict__ al_d, int M,
    const int* __restrict__ ei, int* __restrict__ deg4, int* __restrict__ rank,
    int E, int gemmBlocks) {
  int b = blockIdx.x;
  if (b < gemmBlocks) {
    gemm_body<4, true, true>(b, x, Bp1, a_s, a_d, hf8, al_s, al_d, M);
  } else {
    int b2 = b - gemmBlocks;
    int i = b2 * 256 + threadIdx.x;
    int c = b2 & (NCPY - 1);
    if (i < E) rank[i] = atomicAdd(&deg4[(size_t)c * NNODE + ei[E + i]], 1);
  }
}

// ---------------- scan_all: fused scan1+scan23 over 4-copy degrees ----------------
// 196 blocks.  Each block REDUNDANTLY computes all 196 chunk sums (coalesced loads +
// wave reduce; ~5us, no inter-block dependency), LDS-scans them for its blockOff, then
// does the per-element exclusive scan.  Outputs offs[] and per-copy scatter bases
// coff[c][i] = offs[i] + sum_{c'<c} deg4[c'][i].
__global__ __launch_bounds__(256) void scan_all(const int* __restrict__ deg4,
                                                int* __restrict__ offs,
                                                int* __restrict__ coff, int n) {
  __shared__ int ss[256];
  __shared__ int wsum[SCANB * 4];
  int tid = threadIdx.x;
  int wv = tid >> 6, ln = tid & 63;
  // ---- per-chunk sums (all chunks, this block) ----
  for (int k = 0; k < SCANB; ++k) {
    int idx = k * 256 + tid;
    int v = 0;
    if (idx < n)
      v = deg4[idx] + deg4[n + idx] + deg4[2 * n + idx] + deg4[3 * n + idx];
#pragma unroll
    for (int o = 1; o < 64; o <<= 1) v += __shfl_xor(v, o);
    if (ln == 0) wsum[k * 4 + wv] = v;
  }
  __syncthreads();
  ss[tid] = 0;
  if (tid < SCANB)
    ss[tid] = wsum[tid * 4] + wsum[tid * 4 + 1] + wsum[tid * 4 + 2] + wsum[tid * 4 + 3];
  __syncthreads();
  // ---- inclusive scan of the 196 chunk sums ----
#pragma unroll
  for (int o = 1; o < 256; o <<= 1) {
    int t = (tid >= o) ? ss[tid - o] : 0;
    __syncthreads();
    ss[tid] += t;
    __syncthreads();
  }
  int blockOff = (blockIdx.x == 0) ? 0 : ss[blockIdx.x - 1];
  // ---- per-element exclusive scan within this block's chunk ----
  int i = blockIdx.x * 256 + tid;
  int d0 = 0, d1 = 0, d2 = 0, d3 = 0;
  if (i < n) {
    d0 = deg4[i]; d1 = deg4[n + i]; d2 = deg4[2 * n + i]; d3 = deg4[3 * n + i];
  }
  int tot = d0 + d1 + d2 + d3;
  __syncthreads();
  ss[tid] = tot;
  __syncthreads();
#pragma unroll
  for (int o = 1; o < 256; o <<= 1) {
    int t = (tid >= o) ? ss[tid - o] : 0;
    __syncthreads();
    ss[tid] += t;
    __syncthreads();
  }
  int ex = ss[tid] - tot + blockOff;
  if (i < n) {
    offs[i] = ex;
    coff[i] = ex;
    coff[n + i] = ex + d0;
    coff[2 * n + i] = ex + d0 + d1;
    coff[3 * n + i] = ex + d0 + d1 + d2;
    if (i == n - 1) offs[n] = ex + tot;   // offs[N] = E
  }
}

// ---------------- edge scatter (atomic-free; rank + per-copy base) ----------------
__global__ __launch_bounds__(256) void scatter_kernel(
    const int* __restrict__ ei, const int* __restrict__ coff,
    const int* __restrict__ rank, int* __restrict__ csr_src, int E) {
  int i = blockIdx.x * 256 + threadIdx.x;
  if (i < E) {
    int c = (i >> 8) & (NCPY - 1);    // same copy mapping as count (block index & 3)
    int dst = ei[E + i];
    csr_src[coff[(size_t)c * NNODE + dst] + rank[i]] = ei[i];
  }
}

__global__ __launch_bounds__(256) void gemm2_kernel(
    const u16* __restrict__ h1bf, const u16* __restrict__ Bp2,
    const float* __restrict__ a_s, const float* __restrict__ a_d,
    void* __restrict__ hf8, float* __restrict__ al_s, float* __restrict__ al_d, int M) {
  gemm_body<2, false, true>(blockIdx.x, h1bf, Bp2, a_s, a_d, hf8, al_s, al_d, M);
}

// ---------------- aggregation (R4-proven): 8-edge chunks, depth-1 prefetch ----------
// Weight phase inline & unnormalized: w = exp(lrelu(e))/4 (fp16-safe); per-head divide at
// the end.  Heads separated via packed-fp16 pk_fma: acc01=(h0,h1), acc23=(h2,h3) of
// channel `lane`.  F8: features are bf8(e5m2) 256B rows; conversion to fp16 is ONE
// v_perm_b32 per half2 (e5m2 = truncated fp16: h = byte<<8).  Per edge: 2 readlane +
// [2 perm] + 2 pk_fma.
template <bool FINAL, bool F8>
__global__ __launch_bounds__(256) void agg_kernel(const void* __restrict__ feat,
                                                  const float4* __restrict__ al_s4,
                                                  const float4* __restrict__ al_d4,
                                                  const int* __restrict__ offs,
                                                  const int* __restrict__ csr,
                                                  const float* __restrict__ bias,
                                                  void* __restrict__ out_v, int n) {
  int lane = threadIdx.x & 63;
  int node = blockIdx.x * 4 + (threadIdx.x >> 6);
  if (node >= n) return;
  float4 ad = al_d4[node];
  int lj = lane & 7;           // edge slot within chunk (weight lanes)
  int hsel = (lane >> 3) & 3;  // head handled by this lane in the weight phase
  float adv = hsel == 0 ? ad.x : (hsel == 1 ? ad.y : (hsel == 2 ? ad.z : ad.w));
  h2 acc01 = {(__fp16)0.f, (__fp16)0.f};
  h2 acc23 = {(__fp16)0.f, (__fp16)0.f};
  float dacc = 0.f;            // per-head denom partial (valid on lanes 0,8,16,24)
  int s = offs[node], e = offs[node + 1];
  int nch = (e - s + 7) >> 3;
  int i = s;
  // byte offset into feature row: F8 rows are 256B (u32/lane), else 512B (uint2/lane)
  int voff = F8 ? lane * 4 : lane * 8;

  int vidx = 0;
  float4 as = make_float4(0.f, 0.f, 0.f, 0.f);
  uint2 hv[8];
  if (nch > 0) {
    int id0 = i + lj; if (id0 >= e) id0 = e - 1;   // clamp: masked by w=0 later
    vidx = csr[id0];
    as = al_s4[vidx];
#pragma unroll
    for (int j = 0; j < 8; ++j) {
      int sa = __builtin_amdgcn_readlane(vidx, j);
      if (F8) hv[j].x = *(const u32*)((const char*)feat + (size_t)sa * 256 + voff);
      else    hv[j]   = *(const uint2*)((const char*)feat + (size_t)sa * 512 + voff);
    }
  }

  for (int ch = 0; ch < nch; ++ch) {
    bool last = (ch + 1 == nch);
    // ---- weight phase: unnormalized w, folded 1/4 scale (cancels in divide) ----
    float asv = hsel == 0 ? as.x : (hsel == 1 ? as.y : (hsel == 2 ? as.z : as.w));
    float ev = asv + adv;
    ev = ev >= 0.f ? ev : NEG * ev;
    float wv = __expf(ev - 1.3862944f);            // exp(lrelu(e)) / 4
    if (i + lj >= e) wv = 0.f;                     // mask padded slots
    float t = wv;
    t += __shfl_xor(t, 1); t += __shfl_xor(t, 2); t += __shfl_xor(t, 4);
    dacc += t;                                     // lanes 0,8,16,24 hold head sums
    // pack: lane j (0..7) -> (w_h0,w_h1) of edge j; lane 16+j -> (w_h2,w_h3)
    float w8 = __shfl_xor(wv, 8);
    union { h2 h; u32 u; } pc;
    pc.h = __builtin_amdgcn_cvt_pkrtz(wv, w8);
    // ---- prefetch next chunk ----
    int vidx_n = 0;
    float4 as_n = make_float4(0.f, 0.f, 0.f, 0.f);
    uint2 hn[8];
    if (!last) {
      int id1 = i + 8 + lj; if (id1 >= e) id1 = e - 1;
      vidx_n = csr[id1];
      as_n = al_s4[vidx_n];
#pragma unroll
      for (int j = 0; j < 8; ++j) {
        int sa = __builtin_amdgcn_readlane(vidx_n, j);
        if (F8) hn[j].x = *(const u32*)((const char*)feat + (size_t)sa * 256 + voff);
        else    hn[j]   = *(const uint2*)((const char*)feat + (size_t)sa * 512 + voff);
      }
    }
    // ---- accumulate current chunk ----
#pragma unroll
    for (int j = 0; j < 8; ++j) {
      u32 w01 = (u32)__builtin_amdgcn_readlane((int)pc.u, j);
      u32 w23 = (u32)__builtin_amdgcn_readlane((int)pc.u, 16 + j);
      u32 f01, f23;
      if (F8) {
        // e5m2 byte -> fp16 in high byte of each u16 lane (exact)
        f01 = __builtin_amdgcn_perm(0u, hv[j].x, 0x01080008u);  // {0,b0 | 0,b1}
        f23 = __builtin_amdgcn_perm(0u, hv[j].x, 0x03080208u);  // {0,b2 | 0,b3}
      } else {
        f01 = hv[j].x; f23 = hv[j].y;
      }
      acc01 += u2h2(w01) * u2h2(f01);
      acc23 += u2h2(w23) * u2h2(f23);
    }
    if (!last) {
      vidx = vidx_n; as = as_n;
#pragma unroll
      for (int j = 0; j < 8; ++j) hv[j] = hn[j];
    }
    i += 8;
  }
  float d0 = readlane_f(dacc, 0), d1 = readlane_f(dacc, 8);
  float d2 = readlane_f(dacc, 16), d3 = readlane_f(dacc, 24);
  float val = 0.25f * ((float)acc01.x / (d0 + 1e-16f) + (float)acc01.y / (d1 + 1e-16f) +
                       (float)acc23.x / (d2 + 1e-16f) + (float)acc23.y / (d3 + 1e-16f)) +
              bias[lane];
  if (!FINAL) {
    // layer-1 output: relu + fp16 (feeds layer-2 MFMA GEMM directly)
    ((u16*)out_v)[(size_t)node * HID + lane] = f2h(fmaxf(val, 0.f));
  } else {
    float mx = val;
#pragma unroll
    for (int o = 32; o >= 1; o >>= 1) mx = fmaxf(mx, __shfl_xor(mx, o));
    float ex = __expf(val - mx);
    float sm = ex;
#pragma unroll
    for (int o = 32; o >= 1; o >>= 1) sm += __shfl_xor(sm, o);
    ((float*)out_v)[(size_t)node * HID + lane] = (val - mx) - logf(sm);
  }
}

// ---------------- launch ----------------
extern "C" void kernel_launch(void* const* d_in, const int* in_sizes, int n_in,
                              void* d_out, int out_size, void* d_ws, size_t ws_size,
                              hipStream_t stream) {
  const float* x   = (const float*)d_in[0];
  const int*   ei  = (const int*)d_in[1];   // int32 (JAX x64 disabled canonicalizes int64)
  const float* W1  = (const float*)d_in[2];
  const float* as1 = (const float*)d_in[3];
  const float* ad1 = (const float*)d_in[4];
  const float* b1  = (const float*)d_in[5];
  const float* W2  = (const float*)d_in[6];
  const float* as2 = (const float*)d_in[7];
  const float* ad2 = (const float*)d_in[8];
  const float* b2  = (const float*)d_in[9];
  float* out = (float*)d_out;

  const int N = NNODE;
  const int E = in_sizes[1] / 2;

  char* base = (char*)d_ws;
  size_t off = 0;
  auto alloc = [&](size_t bytes) -> void* {
    void* p = base + off;
    off += (bytes + 255) & ~(size_t)255;
    return p;
  };
  u32*    hf8    = (u32*)alloc((size_t)N * 256);          // 12.8 MB features bf8 [node][ch][head]
                                                          // (layer-1, then REUSED for layer-2)
  u16*    h1bf   = (u16*)alloc((size_t)MPAD * HID * 2);   // 6.4 MB fp16 layer-1 out (padded)
  u16*    Bp1    = (u16*)alloc((size_t)FIN * NC * 2);     // packed W1 (fp16)
  u16*    Bp2    = (u16*)alloc((size_t)HID * NC * 2);     // packed W2 (fp16)
  float*  al_s   = (float*)alloc((size_t)N * NH * 4);
  float*  al_d   = (float*)alloc((size_t)N * NH * 4);
  int*    deg4   = (int*)alloc((size_t)NCPY * N * 4);     // 0.8 MB 4-copy histogram
  int*    coff   = (int*)alloc((size_t)NCPY * N * 4);     // 0.8 MB per-copy scatter bases
  int*    offs   = (int*)alloc((size_t)(N + 1) * 4);
  int*    rank   = (int*)alloc((size_t)E * 4);
  int*    csr    = (int*)alloc((size_t)(E + 16) * 4);

  const int edgeBlocks = (E + 255) / 256;       // 3125
  const int gemmBlocks = MPAD / 64;             // 782
  const int nodeBlocks = (N + 3) / 4;           // 12500: 4 waves/block, HW-balanced
  const int packBlocks = (FIN * NC + HID * NC + 255) / 256;  // 192
  const int zeroBlocks = (NCPY * N + 255) / 256;             // 782

  // --- kernel 1: weight pack + deg4 zero ---
  pack_zero<<<packBlocks + zeroBlocks, 256, 0, stream>>>(W1, W2, Bp1, Bp2, deg4, packBlocks, N);

  // --- kernel 2: 4-copy degree count (atomics) overlapped with layer-1 GEMM (MFMA) ---
  count_gemm1<<<gemmBlocks + edgeBlocks, 256, 0, stream>>>(
      x, Bp1, as1, ad1, hf8, al_s, al_d, N,
      ei, deg4, rank, E, gemmBlocks);

  // --- kernel 3: fused scan (offs + per-copy bases) ---
  scan_all<<<SCANB, 256, 0, stream>>>(deg4, offs, coff, N);

  // --- kernel 4: scatter ---
  scatter_kernel<<<edgeBlocks, 256, 0, stream>>>(ei, coff, rank, csr, E);

  // --- layer-1 aggregation ---
  agg_kernel<false, true><<<nodeBlocks, 256, 0, stream>>>(hf8, (const float4*)al_s, (const float4*)al_d,
                                                          offs, csr, b1, h1bf, N);

  // --- layer 2 (bf8 features; hf8 reused stream-ordered) ---
  gemm2_kernel<<<gemmBlocks, 256, 0, stream>>>(h1bf, Bp2, as2, ad2, hf8, al_s, al_d, N);
  agg_kernel<true, true><<<nodeBlocks, 256, 0, stream>>>(hf8, (const float4*)al_s, (const float4*)al_d,
                                                         offs, csr, b2, out, N);
}

// Round 11
// 237.166 us; speedup vs baseline: 1.3830x; 1.3830x over previous
//
#include <hip/hip_runtime.h>
#include <math.h>

// Problem constants (GATModel: N=50000, E=800000, F_IN=128, HID=OUT=64, H=4)
constexpr int NNODE = 50000;
constexpr int FIN   = 128;
constexpr int HID   = 64;
constexpr int NH    = 4;
constexpr int NC    = 256;   // NH * HID
constexpr float NEG = 0.2f;
constexpr int MPAD  = 50048; // NNODE padded to 64-row tiles (782*64)
constexpr int SCANB = (NNODE + 255) / 256;  // 196
constexpr int NCPY  = 4;     // histogram copies (atomic same-address chains 16 -> ~4)

typedef unsigned short u16;
typedef unsigned int   u32;
typedef __fp16 h16x8 __attribute__((ext_vector_type(8)));
typedef __fp16 h2    __attribute__((ext_vector_type(2)));
typedef float  f32x4 __attribute__((ext_vector_type(4)));

__device__ __forceinline__ u16 f2h(float f) {
  union { __fp16 h; u16 u; } c; c.h = (__fp16)f; return c.u;
}
__device__ __forceinline__ h2 u2h2(u32 u) {
  union { u32 u; h2 h; } c; c.u = u; return c.h;
}
__device__ __forceinline__ float readlane_f(float v, int l) {
  return __int_as_float(__builtin_amdgcn_readlane(__float_as_int(v), l));
}
// fp16 bits -> bf8(e5m2) bits, round-to-nearest-even (e5m2 = truncated fp16)
__device__ __forceinline__ u32 h2bf8(u16 hx) {
  return ((u32)hx + 0x7Fu + ((hx >> 8) & 1u)) >> 8;
}

// ---------------- kernel 1: 4-copy degree count + weight packing + deg4 zero ----------
// Blocks [0,edgeBlocks): rank[i] = atomicAdd(&deg4[(b&3)*N + dst], 1).
// Blocks [edgeBlocks,+packBlocks): pack W1/W2 fp32 -> fp16 MFMA B-fragment order.
// deg4 is zeroed by host-side hipMemsetAsync (proven cheap in R8).
__global__ __launch_bounds__(256) void count_pack(const int* __restrict__ ei, int* __restrict__ deg4,
                                                  int* __restrict__ rank, int E, int edgeBlocks,
                                                  const float* __restrict__ W1, const float* __restrict__ W2,
                                                  u16* __restrict__ Bp1, u16* __restrict__ Bp2) {
  int b = blockIdx.x;
  if (b < edgeBlocks) {
    int i = b * 256 + threadIdx.x;
    int c = b & (NCPY - 1);
    if (i < E) rank[i] = atomicAdd(&deg4[(size_t)c * NNODE + ei[E + i]], 1);
  } else {
    int i = (b - edgeBlocks) * 256 + threadIdx.x;
    const int t1 = FIN * NC;
    const int t2 = HID * NC;
    if (i < t1) {
      int k = i >> 8, c = i & 255;
      Bp1[((size_t)(k >> 3) * 256 + c) * 8 + (k & 7)] = f2h(W1[i]);
    } else if (i < t1 + t2) {
      int j = i - t1;
      int k = j >> 8, c = j & 255;
      Bp2[((size_t)(k >> 3) * 256 + c) * 8 + (k & 7)] = f2h(W2[j]);
    }
  }
}

// ---------------- scan phase 1: per-block sums of merged (4-copy) degrees ----------------
__global__ __launch_bounds__(256) void scan_phase1(const int* __restrict__ deg4,
                                                   int* __restrict__ blockSums, int n) {
  __shared__ int sm[256];
  int tid = threadIdx.x;
  int i = blockIdx.x * 256 + tid;
  int v = 0;
  if (i < n)
    v = deg4[i] + deg4[n + i] + deg4[2 * n + i] + deg4[3 * n + i];
  sm[tid] = v;
  __syncthreads();
#pragma unroll
  for (int o = 128; o > 0; o >>= 1) {
    if (tid < o) sm[tid] += sm[tid + o];
    __syncthreads();
  }
  if (tid == 0) blockSums[blockIdx.x] = sm[0];
}

// ---------------- scan phases 2+3 fused: offs + per-copy scatter bases ----------------
__global__ __launch_bounds__(256) void scan_phase23(const int* __restrict__ blockSums,
                                                    const int* __restrict__ deg4,
                                                    int* __restrict__ offs,
                                                    int* __restrict__ coff, int n) {
  __shared__ int ss[256];
  __shared__ int sm[256];
  int tid = threadIdx.x;
  ss[tid] = (tid < SCANB) ? blockSums[tid] : 0;
  __syncthreads();
#pragma unroll
  for (int o = 1; o < 256; o <<= 1) {
    int t = (tid >= o) ? ss[tid - o] : 0;
    __syncthreads();
    ss[tid] += t;
    __syncthreads();
  }
  int blockOff = (blockIdx.x == 0) ? 0 : ss[blockIdx.x - 1];
  int i = blockIdx.x * 256 + tid;
  int d0 = 0, d1 = 0, d2 = 0, d3 = 0;
  if (i < n) {
    d0 = deg4[i]; d1 = deg4[n + i]; d2 = deg4[2 * n + i]; d3 = deg4[3 * n + i];
  }
  int tot = d0 + d1 + d2 + d3;
  sm[tid] = tot;
  __syncthreads();
#pragma unroll
  for (int o = 1; o < 256; o <<= 1) {
    int t = (tid >= o) ? sm[tid - o] : 0;
    __syncthreads();
    sm[tid] += t;
    __syncthreads();
  }
  int ex = sm[tid] - tot + blockOff;
  if (i < n) {
    offs[i] = ex;
    coff[i] = ex;
    coff[n + i] = ex + d0;
    coff[2 * n + i] = ex + d0 + d1;
    coff[3 * n + i] = ex + d0 + d1 + d2;
  }
  if (blockIdx.x == SCANB - 1 && tid == 255) offs[n] = ss[SCANB - 1];  // offs[N] = E
}

// ---------------- MFMA fp16 GEMM body ----------------
// C[M,256] = A[M,K] @ B[K,256]fp16 (B pre-packed in fragment order).
// A-frag: lane holds A[m = lane&15][k = (lane>>4)*8 + j]
// B-frag: lane holds B[k = (lane>>4)*8 + j][n = lane&15]  (packed Bp)
// D: col = lane&15, row = (lane>>4)*4 + reg   [m89/m91-verified layouts]
// F8: feature store as bf8(e5m2) packed 4 heads/u32 at [node][channel][head] (256B rows);
//     else fp16 at [node][c][h] (512B rows).
template <int KS, bool AF32, bool F8>  // K = 32*KS
__device__ __forceinline__ void gemm_body(
    int bx, const void* __restrict__ Aptr, const u16* __restrict__ Bp,
    const float* __restrict__ a_s, const float* __restrict__ a_d,
    void* __restrict__ feat, float* __restrict__ al_s, float* __restrict__ al_d, int M) {
  const int K = 32 * KS;
  int lane = threadIdx.x & 63;
  int wv = threadIdx.x >> 6;
  int q = lane >> 4, r = lane & 15;
  int m0 = bx * 64 + wv * 16;

  h16x8 af[KS];
  if (AF32) {
    int ar = m0 + r; if (ar >= M) ar = M - 1;   // x has exactly M rows; clamp (stores guarded)
    const float* arow = (const float*)Aptr + (size_t)ar * K + q * 8;
#pragma unroll
    for (int ks = 0; ks < KS; ++ks) {
      float4 v0 = *(const float4*)(arow + ks * 32);
      float4 v1 = *(const float4*)(arow + ks * 32 + 4);
      union { h16x8 v; h2 p[4]; } u;
      u.p[0] = __builtin_amdgcn_cvt_pkrtz(v0.x, v0.y);
      u.p[1] = __builtin_amdgcn_cvt_pkrtz(v0.z, v0.w);
      u.p[2] = __builtin_amdgcn_cvt_pkrtz(v1.x, v1.y);
      u.p[3] = __builtin_amdgcn_cvt_pkrtz(v1.z, v1.w);
      af[ks] = u.v;
    }
  } else {
    const u16* arow = (const u16*)Aptr + (size_t)(m0 + r) * K + q * 8;  // padded buffer
#pragma unroll
    for (int ks = 0; ks < KS; ++ks) af[ks] = *(const h16x8*)(arow + ks * 32);
  }

  int node_base = m0 + q * 4;
  u32 pk8[4][4];
  if (F8) {
#pragma unroll
    for (int a = 0; a < 4; ++a)
#pragma unroll
      for (int b = 0; b < 4; ++b) pk8[a][b] = 0u;
  }
#pragma unroll
  for (int h = 0; h < NH; ++h) {
    f32x4 acc[4];
#pragma unroll
    for (int c4 = 0; c4 < 4; ++c4) {
      acc[c4] = (f32x4){0.f, 0.f, 0.f, 0.f};
      const u16* bp = Bp + ((size_t)q * 256 + (h * 4 + c4) * 16 + r) * 8;
#pragma unroll
      for (int ks = 0; ks < KS; ++ks) {
        h16x8 bf = *(const h16x8*)(bp + (size_t)ks * 4 * 256 * 8);
        acc[c4] = __builtin_amdgcn_mfma_f32_16x16x32_f16(af[ks], bf, acc[c4], 0, 0, 0);
      }
    }
    // epilogue for this head: alpha partials + packed stores
    float ps[4] = {0.f, 0.f, 0.f, 0.f}, pd[4] = {0.f, 0.f, 0.f, 0.f};
#pragma unroll
    for (int c4 = 0; c4 < 4; ++c4) {
      float sa = a_s[h * HID + c4 * 16 + r];
      float da = a_d[h * HID + c4 * 16 + r];
#pragma unroll
      for (int reg = 0; reg < 4; ++reg) {
        float v = acc[c4][reg];
        ps[reg] += v * sa;
        pd[reg] += v * da;
        if (F8) {
          pk8[c4][reg] |= h2bf8(f2h(v)) << (8 * h);
        } else {
          int node = node_base + reg;
          if (node < M) ((u16*)feat)[(size_t)node * NC + (c4 * 16 + r) * NH + h] = f2h(v);
        }
      }
    }
#pragma unroll
    for (int reg = 0; reg < 4; ++reg) {
#pragma unroll
      for (int o = 1; o < 16; o <<= 1) {
        ps[reg] += __shfl_xor(ps[reg], o);
        pd[reg] += __shfl_xor(pd[reg], o);
      }
      int node = node_base + reg;
      if (r == 0 && node < M) {
        al_s[node * NH + h] = ps[reg];
        al_d[node * NH + h] = pd[reg];
      }
    }
  }
  if (F8) {
    // one u32 store per (c4,reg): 4 bf8 heads of channel c4*16+r for node node_base+reg
#pragma unroll
    for (int c4 = 0; c4 < 4; ++c4)
#pragma unroll
      for (int reg = 0; reg < 4; ++reg) {
        int node = node_base + reg;
        if (node < M)
          *(u32*)((char*)feat + (size_t)node * 256 + (c4 * 16 + r) * 4) = pk8[c4][reg];
      }
  }
}

// ---------------- fused: gemm layer-1 + atomic-free edge scatter ----------------
__global__ __launch_bounds__(256) void gemm1_scatter(
    const float* __restrict__ x, const u16* __restrict__ Bp1,
    const float* __restrict__ a_s, const float* __restrict__ a_d,
    void* __restrict__ hf8, float* __restrict__ al_s, float* __restrict__ al_d, int M,
    const int* __restrict__ ei, const int* __restrict__ coff, const int* __restrict__ rank,
    int* __restrict__ csr_src, int E, int gemmBlocks) {
  int b = blockIdx.x;
  if (b < gemmBlocks) {
    gemm_body<4, true, true>(b, x, Bp1, a_s, a_d, hf8, al_s, al_d, M);
  } else {
    int b2 = b - gemmBlocks;
    int i = b2 * 256 + threadIdx.x;
    int c = b2 & (NCPY - 1);          // same copy mapping as count (edge-block & 3)
    if (i < E) {
      int dst = ei[E + i];
      csr_src[coff[(size_t)c * NNODE + dst] + rank[i]] = ei[i];   // no atomic
    }
  }
}

__global__ __launch_bounds__(256) void gemm2_kernel(
    const u16* __restrict__ h1bf, const u16* __restrict__ Bp2,
    const float* __restrict__ a_s, const float* __restrict__ a_d,
    void* __restrict__ hf8, float* __restrict__ al_s, float* __restrict__ al_d, int M) {
  gemm_body<2, false, true>(blockIdx.x, h1bf, Bp2, a_s, a_d, hf8, al_s, al_d, M);
}

// ---------------- aggregation (R4-proven): 8-edge chunks, depth-1 prefetch ----------
// Weight phase inline & unnormalized: w = exp(lrelu(e))/4 (fp16-safe); per-head divide at
// the end.  Heads separated via packed-fp16 pk_fma: acc01=(h0,h1), acc23=(h2,h3) of
// channel `lane`.  F8: features are bf8(e5m2) 256B rows; conversion to fp16 is ONE
// v_perm_b32 per half2 (e5m2 = truncated fp16: h = byte<<8).  Per edge: 2 readlane +
// [2 perm] + 2 pk_fma.
template <bool FINAL, bool F8>
__global__ __launch_bounds__(256) void agg_kernel(const void* __restrict__ feat,
                                                  const float4* __restrict__ al_s4,
                                                  const float4* __restrict__ al_d4,
                                                  const int* __restrict__ offs,
                                                  const int* __restrict__ csr,
                                                  const float* __restrict__ bias,
                                                  void* __restrict__ out_v, int n) {
  int lane = threadIdx.x & 63;
  int node = blockIdx.x * 4 + (threadIdx.x >> 6);
  if (node >= n) return;
  float4 ad = al_d4[node];
  int lj = lane & 7;           // edge slot within chunk (weight lanes)
  int hsel = (lane >> 3) & 3;  // head handled by this lane in the weight phase
  float adv = hsel == 0 ? ad.x : (hsel == 1 ? ad.y : (hsel == 2 ? ad.z : ad.w));
  h2 acc01 = {(__fp16)0.f, (__fp16)0.f};
  h2 acc23 = {(__fp16)0.f, (__fp16)0.f};
  float dacc = 0.f;            // per-head denom partial (valid on lanes 0,8,16,24)
  int s = offs[node], e = offs[node + 1];
  int nch = (e - s + 7) >> 3;
  int i = s;
  // byte offset into feature row: F8 rows are 256B (u32/lane), else 512B (uint2/lane)
  int voff = F8 ? lane * 4 : lane * 8;

  int vidx = 0;
  float4 as = make_float4(0.f, 0.f, 0.f, 0.f);
  uint2 hv[8];
  if (nch > 0) {
    int id0 = i + lj; if (id0 >= e) id0 = e - 1;   // clamp: masked by w=0 later
    vidx = csr[id0];
    as = al_s4[vidx];
#pragma unroll
    for (int j = 0; j < 8; ++j) {
      int sa = __builtin_amdgcn_readlane(vidx, j);
      if (F8) hv[j].x = *(const u32*)((const char*)feat + (size_t)sa * 256 + voff);
      else    hv[j]   = *(const uint2*)((const char*)feat + (size_t)sa * 512 + voff);
    }
  }

  for (int ch = 0; ch < nch; ++ch) {
    bool last = (ch + 1 == nch);
    // ---- weight phase: unnormalized w, folded 1/4 scale (cancels in divide) ----
    float asv = hsel == 0 ? as.x : (hsel == 1 ? as.y : (hsel == 2 ? as.z : as.w));
    float ev = asv + adv;
    ev = ev >= 0.f ? ev : NEG * ev;
    float wv = __expf(ev - 1.3862944f);            // exp(lrelu(e)) / 4
    if (i + lj >= e) wv = 0.f;                     // mask padded slots
    float t = wv;
    t += __shfl_xor(t, 1); t += __shfl_xor(t, 2); t += __shfl_xor(t, 4);
    dacc += t;                                     // lanes 0,8,16,24 hold head sums
    // pack: lane j (0..7) -> (w_h0,w_h1) of edge j; lane 16+j -> (w_h2,w_h3)
    float w8 = __shfl_xor(wv, 8);
    union { h2 h; u32 u; } pc;
    pc.h = __builtin_amdgcn_cvt_pkrtz(wv, w8);
    // ---- prefetch next chunk ----
    int vidx_n = 0;
    float4 as_n = make_float4(0.f, 0.f, 0.f, 0.f);
    uint2 hn[8];
    if (!last) {
      int id1 = i + 8 + lj; if (id1 >= e) id1 = e - 1;
      vidx_n = csr[id1];
      as_n = al_s4[vidx_n];
#pragma unroll
      for (int j = 0; j < 8; ++j) {
        int sa = __builtin_amdgcn_readlane(vidx_n, j);
        if (F8) hn[j].x = *(const u32*)((const char*)feat + (size_t)sa * 256 + voff);
        else    hn[j]   = *(const uint2*)((const char*)feat + (size_t)sa * 512 + voff);
      }
    }
    // ---- accumulate current chunk ----
#pragma unroll
    for (int j = 0; j < 8; ++j) {
      u32 w01 = (u32)__builtin_amdgcn_readlane((int)pc.u, j);
      u32 w23 = (u32)__builtin_amdgcn_readlane((int)pc.u, 16 + j);
      u32 f01, f23;
      if (F8) {
        // e5m2 byte -> fp16 in high byte of each u16 lane (exact)
        f01 = __builtin_amdgcn_perm(0u, hv[j].x, 0x01080008u);  // {0,b0 | 0,b1}
        f23 = __builtin_amdgcn_perm(0u, hv[j].x, 0x03080208u);  // {0,b2 | 0,b3}
      } else {
        f01 = hv[j].x; f23 = hv[j].y;
      }
      acc01 += u2h2(w01) * u2h2(f01);
      acc23 += u2h2(w23) * u2h2(f23);
    }
    if (!last) {
      vidx = vidx_n; as = as_n;
#pragma unroll
      for (int j = 0; j < 8; ++j) hv[j] = hn[j];
    }
    i += 8;
  }
  float d0 = readlane_f(dacc, 0), d1 = readlane_f(dacc, 8);
  float d2 = readlane_f(dacc, 16), d3 = readlane_f(dacc, 24);
  float val = 0.25f * ((float)acc01.x / (d0 + 1e-16f) + (float)acc01.y / (d1 + 1e-16f) +
                       (float)acc23.x / (d2 + 1e-16f) + (float)acc23.y / (d3 + 1e-16f)) +
              bias[lane];
  if (!FINAL) {
    // layer-1 output: relu + fp16 (feeds layer-2 MFMA GEMM directly)
    ((u16*)out_v)[(size_t)node * HID + lane] = f2h(fmaxf(val, 0.f));
  } else {
    float mx = val;
#pragma unroll
    for (int o = 32; o >= 1; o >>= 1) mx = fmaxf(mx, __shfl_xor(mx, o));
    float ex = __expf(val - mx);
    float sm = ex;
#pragma unroll
    for (int o = 32; o >= 1; o >>= 1) sm += __shfl_xor(sm, o);
    ((float*)out_v)[(size_t)node * HID + lane] = (val - mx) - logf(sm);
  }
}

// ---------------- launch ----------------
extern "C" void kernel_launch(void* const* d_in, const int* in_sizes, int n_in,
                              void* d_out, int out_size, void* d_ws, size_t ws_size,
                              hipStream_t stream) {
  const float* x   = (const float*)d_in[0];
  const int*   ei  = (const int*)d_in[1];   // int32 (JAX x64 disabled canonicalizes int64)
  const float* W1  = (const float*)d_in[2];
  const float* as1 = (const float*)d_in[3];
  const float* ad1 = (const float*)d_in[4];
  const float* b1  = (const float*)d_in[5];
  const float* W2  = (const float*)d_in[6];
  const float* as2 = (const float*)d_in[7];
  const float* ad2 = (const float*)d_in[8];
  const float* b2  = (const float*)d_in[9];
  float* out = (float*)d_out;

  const int N = NNODE;
  const int E = in_sizes[1] / 2;

  char* base = (char*)d_ws;
  size_t off = 0;
  auto alloc = [&](size_t bytes) -> void* {
    void* p = base + off;
    off += (bytes + 255) & ~(size_t)255;
    return p;
  };
  u32*    hf8    = (u32*)alloc((size_t)N * 256);          // 12.8 MB features bf8 [node][ch][head]
                                                          // (layer-1, then REUSED for layer-2)
  u16*    h1bf   = (u16*)alloc((size_t)MPAD * HID * 2);   // 6.4 MB fp16 layer-1 out (padded)
  u16*    Bp1    = (u16*)alloc((size_t)FIN * NC * 2);     // packed W1 (fp16)
  u16*    Bp2    = (u16*)alloc((size_t)HID * NC * 2);     // packed W2 (fp16)
  float*  al_s   = (float*)alloc((size_t)N * NH * 4);
  float*  al_d   = (float*)alloc((size_t)N * NH * 4);
  int*    deg4   = (int*)alloc((size_t)NCPY * N * 4);     // 0.8 MB 4-copy histogram
  int*    coff   = (int*)alloc((size_t)NCPY * N * 4);     // 0.8 MB per-copy scatter bases
  int*    offs   = (int*)alloc((size_t)(N + 1) * 4);
  int*    rank   = (int*)alloc((size_t)E * 4);
  int*    csr    = (int*)alloc((size_t)(E + 16) * 4);
  int*    bsums  = (int*)alloc(256 * 4);

  const int edgeBlocks = (E + 255) / 256;       // 3125
  const int gemmBlocks = MPAD / 64;             // 782
  const int nodeBlocks = (N + 3) / 4;           // 12500: 4 waves/block, HW-balanced
  const int packBlocks = (FIN * NC + HID * NC + 255) / 256;  // 192

  // --- CSR build + weight pack (R8 structure; ONLY change: 4-copy histogram) ---
  (void)hipMemsetAsync(deg4, 0, (size_t)NCPY * N * 4, stream);
  count_pack<<<edgeBlocks + packBlocks, 256, 0, stream>>>(ei, deg4, rank, E, edgeBlocks, W1, W2, Bp1, Bp2);
  scan_phase1<<<SCANB, 256, 0, stream>>>(deg4, bsums, N);
  scan_phase23<<<SCANB, 256, 0, stream>>>(bsums, deg4, offs, coff, N);

  // --- layer 1 GEMM (MFMA, bf8 feature store) overlapped with edge scatter ---
  gemm1_scatter<<<gemmBlocks + edgeBlocks, 256, 0, stream>>>(
      x, Bp1, as1, ad1, hf8, al_s, al_d, N,
      ei, coff, rank, csr, E, gemmBlocks);
  agg_kernel<false, true><<<nodeBlocks, 256, 0, stream>>>(hf8, (const float4*)al_s, (const float4*)al_d,
                                                          offs, csr, b1, h1bf, N);

  // --- layer 2 (bf8 features; hf8 reused stream-ordered) ---
  gemm2_kernel<<<gemmBlocks, 256, 0, stream>>>(h1bf, Bp2, as2, ad2, hf8, al_s, al_d, N);
  agg_kernel<true, true><<<nodeBlocks, 256, 0, stream>>>(hf8, (const float4*)al_s, (const float4*)al_d,
                                                         offs, csr, b2, out, N);
}